// Round 1
// baseline (1961.020 us; speedup 1.0000x reference)
//
#include <hip/hip_runtime.h>
#include <cstdint>
#include <cstddef>

#define D_MODEL 2048
#define NUM_CLASSES 50257
#define N_PAD 50304          // 393*128
#define N_BASIS 8
#define RANK 4
#define HIDDEN 128
#define B_ROWS 2048
#define KE 2080              // D_MODEL + N_BASIS*RANK
#define LN_EPS 1e-5f

typedef short short8 __attribute__((ext_vector_type(8)));
typedef float f32x4 __attribute__((ext_vector_type(4)));

__device__ __forceinline__ uint16_t f2bf(float f) {
    union { float f; uint32_t u; } c; c.f = f;
    uint32_t r = c.u + 0x7FFFu + ((c.u >> 16) & 1u);   // round-to-nearest-even
    return (uint16_t)(r >> 16);
}

__device__ __forceinline__ short8 pack8(float4 a, float4 b) {
    union { short8 v; uint16_t u[8]; } p;
    p.u[0] = f2bf(a.x); p.u[1] = f2bf(a.y); p.u[2] = f2bf(a.z); p.u[3] = f2bf(a.w);
    p.u[4] = f2bf(b.x); p.u[5] = f2bf(b.y); p.u[6] = f2bf(b.z); p.u[7] = f2bf(b.w);
    return p.v;
}

__device__ __forceinline__ void async16(const void* g, void* l) {
    __builtin_amdgcn_global_load_lds(
        (const __attribute__((address_space(1))) unsigned int*)g,
        (__attribute__((address_space(3))) unsigned int*)l, 16, 0, 0);
}

// ---- x (fp32, 2048x2048) -> Aext bf16 cols [0,2048), ld=KE ----
__global__ void k_cvt_x(const float* __restrict__ x, uint16_t* __restrict__ Aext) {
    int chunk = blockIdx.x * 256 + threadIdx.x;     // 2048*256 chunks of 8
    int b = chunk >> 8, c8 = (chunk & 255) * 8;
    const float4* src = (const float4*)(x + (size_t)b * D_MODEL + c8);
    float4 f0 = src[0], f1 = src[1];
    *(short8*)(Aext + (size_t)b * KE + c8) = pack8(f0, f1);
}

// ---- base_w (fp32, 50257x2048) -> Bext bf16 cols [0,2048), rows padded to N_PAD, ld=KE ----
__global__ void k_cvt_bw(const float* __restrict__ bw, uint16_t* __restrict__ Bext) {
    int row = blockIdx.x;                 // 0..N_PAD-1
    int c8 = threadIdx.x * 8;             // 256 threads cover 2048 cols
    short8 v;
    if (row < NUM_CLASSES) {
        const float4* src = (const float4*)(bw + (size_t)row * D_MODEL + c8);
        v = pack8(src[0], src[1]);
    } else {
        union { short8 s; uint16_t u[8]; } z;
        #pragma unroll
        for (int i = 0; i < 8; i++) z.u[i] = 0;
        v = z.s;
    }
    *(short8*)(Bext + (size_t)row * KE + c8) = v;
}

// ---- basis_B (8, 50257, 4) -> dst[row, coloff + nb*4 + r] = basis_B[nb,row,r], bf16 ----
__global__ void k_cvt_bbt(const float* __restrict__ bB, uint16_t* __restrict__ dst,
                          int ld, int coloff) {
    int row = blockIdx.x * 256 + threadIdx.x;
    if (row >= N_PAD) return;
    union { short8 v[4]; uint16_t u[32]; } p;
    if (row < NUM_CLASSES) {
        #pragma unroll
        for (int nb = 0; nb < N_BASIS; nb++) {
            float4 v = *(const float4*)(bB + ((size_t)nb * NUM_CLASSES + row) * RANK);
            p.u[nb*4+0] = f2bf(v.x); p.u[nb*4+1] = f2bf(v.y);
            p.u[nb*4+2] = f2bf(v.z); p.u[nb*4+3] = f2bf(v.w);
        }
    } else {
        #pragma unroll
        for (int i = 0; i < 32; i++) p.u[i] = 0;
    }
    uint16_t* d = dst + (size_t)row * ld + coloff;
    #pragma unroll
    for (int i = 0; i < 4; i++) *(short8*)(d + i * 8) = p.v[i];
}

// ---- context MLP: linear -> LN -> exact GELU -> linear -> coeffs (2048x8 fp32) ----
__global__ void k_ctx(const float* __restrict__ context, const float* __restrict__ ctx_w,
                      const float* __restrict__ ctx_b, const float* __restrict__ ln_g,
                      const float* __restrict__ ln_b, const float* __restrict__ coeff_w,
                      const float* __restrict__ coeff_b, float* __restrict__ coeffs) {
    __shared__ float sctx[D_MODEL];
    __shared__ float s1[HIDDEN], s2[HIDDEN], sh[HIDDEN];
    int tid = threadIdx.x, b = blockIdx.x;
    const float4* csrc = (const float4*)(context + (size_t)b * D_MODEL);
    for (int i = tid; i < D_MODEL / 4; i += HIDDEN) ((float4*)sctx)[i] = csrc[i];
    __syncthreads();
    const float4* wrow = (const float4*)(ctx_w + (size_t)tid * D_MODEL);
    float acc = 0.f;
    #pragma unroll 4
    for (int k = 0; k < D_MODEL / 4; k++) {
        float4 wv = wrow[k]; float4 cv = ((float4*)sctx)[k];
        acc += wv.x * cv.x + wv.y * cv.y + wv.z * cv.z + wv.w * cv.w;
    }
    float h0 = acc + ctx_b[tid];
    s1[tid] = h0; s2[tid] = h0 * h0;
    __syncthreads();
    for (int off = HIDDEN / 2; off > 0; off >>= 1) {
        if (tid < off) { s1[tid] += s1[tid + off]; s2[tid] += s2[tid + off]; }
        __syncthreads();
    }
    float mu  = s1[0] * (1.f / HIDDEN);
    float var = s2[0] * (1.f / HIDDEN) - mu * mu;
    float hn = (h0 - mu) * rsqrtf(var + LN_EPS) * ln_g[tid] + ln_b[tid];
    float h = 0.5f * hn * (1.f + erff(hn * 0.70710678118654752f));
    sh[tid] = h;
    __syncthreads();
    if (tid < N_BASIS) {
        const float* cw = coeff_w + tid * HIDDEN;
        float a = 0.f;
        #pragma unroll 4
        for (int k = 0; k < HIDDEN; k++) a += cw[k] * sh[k];
        coeffs[b * N_BASIS + tid] = a + coeff_b[tid];
    }
}

// ---- t = x @ basis_A^T ; z_r = sum_nb coeffs*t ; u = coeffs (x) z -> Aext cols [2048,2080) bf16 ----
__global__ void k_zu(const float* __restrict__ x, const float* __restrict__ basis_A,
                     const float* __restrict__ coeffs, uint16_t* __restrict__ Aext) {
    __shared__ float sx[D_MODEL];
    __shared__ float part[128];
    __shared__ float st[32];
    __shared__ float sz[RANK];
    int tid = threadIdx.x, b = blockIdx.x;
    const float4* xs = (const float4*)(x + (size_t)b * D_MODEL);
    for (int i = tid; i < D_MODEL / 4; i += 128) ((float4*)sx)[i] = xs[i];
    __syncthreads();
    int nr = tid & 31, s = tid >> 5;      // 32 outputs x 4 K-slices
    const float4* arow = ((const float4*)(basis_A + (size_t)nr * D_MODEL)) + s * 128;
    const float4* xrow = ((const float4*)sx) + s * 128;
    float acc = 0.f;
    #pragma unroll 4
    for (int k = 0; k < 128; k++) {
        float4 av = arow[k]; float4 xv = xrow[k];
        acc += av.x * xv.x + av.y * xv.y + av.z * xv.z + av.w * xv.w;
    }
    part[tid] = acc;
    __syncthreads();
    if (tid < 32) st[tid] = part[tid] + part[tid + 32] + part[tid + 64] + part[tid + 96];
    __syncthreads();
    if (tid < RANK) {
        float z = 0.f;
        #pragma unroll
        for (int nb = 0; nb < N_BASIS; nb++) z += coeffs[b * N_BASIS + nb] * st[nb * RANK + tid];
        sz[tid] = z;
    }
    __syncthreads();
    if (tid < 32) {
        int nb = tid >> 2, r = tid & 3;
        float u = coeffs[b * N_BASIS + nb] * sz[r];
        Aext[(size_t)b * KE + D_MODEL + tid] = f2bf(u);
    }
}

// ---- main GEMM: C[m,n] = sum_k Aext[m,k]*B[n,k] + base_b[n] ; m97-style 128x128 tile ----
template<bool FULLB>
__global__ __launch_bounds__(256) void k_gemm(
        const uint16_t* __restrict__ Aext,   // B_ROWS x KE bf16
        const uint16_t* __restrict__ Bbuf,   // FULLB: N_PAD x KE ; else Bbt N_PAD x 32
        const float* __restrict__ bw,        // fp32 base_w (fallback staging)
        const float* __restrict__ base_b,
        float* __restrict__ out) {
    __shared__ uint16_t sA[128 * 32];
    __shared__ uint16_t sB[128 * 32];
    const int tid = threadIdx.x;
    const int lane = tid & 63, w = tid >> 6;
    const int bm = blockIdx.x, bn = blockIdx.y;
    const int wm = (w >> 1) * 64, wn = (w & 1) * 64;
    f32x4 acc[4][4] = {};

    for (int kk = 0; kk < KE; kk += 32) {
        #pragma unroll
        for (int it = 0; it < 2; it++) {
            int chunk = it * 256 + tid;
            int r = chunk >> 2, c = chunk & 3;
            async16(Aext + (size_t)(bm * 128 + r) * KE + kk + c * 8,
                    sA + it * 2048 + w * 512);
        }
        if constexpr (FULLB) {
            #pragma unroll
            for (int it = 0; it < 2; it++) {
                int chunk = it * 256 + tid;
                int r = chunk >> 2, c = chunk & 3;
                async16(Bbuf + (size_t)(bn * 128 + r) * KE + kk + c * 8,
                        sB + it * 2048 + w * 512);
            }
        } else {
            if (kk < D_MODEL) {
                #pragma unroll
                for (int it = 0; it < 2; it++) {
                    int chunk = it * 256 + tid;
                    int r = chunk >> 2, c = chunk & 3;
                    int gr = bn * 128 + r;
                    short8 v;
                    if (gr < NUM_CLASSES) {
                        const float4* s = (const float4*)(bw + (size_t)gr * D_MODEL + kk + c * 8);
                        v = pack8(s[0], s[1]);
                    } else {
                        union { short8 s; uint16_t u[8]; } z;
                        #pragma unroll
                        for (int i = 0; i < 8; i++) z.u[i] = 0;
                        v = z.s;
                    }
                    *(short8*)(sB + chunk * 8) = v;
                }
            } else {
                #pragma unroll
                for (int it = 0; it < 2; it++) {
                    int chunk = it * 256 + tid;
                    int r = chunk >> 2, c = chunk & 3;
                    async16(Bbuf + (size_t)(bn * 128 + r) * 32 + c * 8,
                            sB + it * 2048 + w * 512);
                }
            }
        }
        __syncthreads();
        short8 af[4], bf[4];
        #pragma unroll
        for (int i = 0; i < 4; i++)
            af[i] = *(const short8*)(sA + (wm + i * 16 + (lane & 15)) * 32 + (lane >> 4) * 8);
        #pragma unroll
        for (int j = 0; j < 4; j++)
            bf[j] = *(const short8*)(sB + (wn + j * 16 + (lane & 15)) * 32 + (lane >> 4) * 8);
        #pragma unroll
        for (int i = 0; i < 4; i++)
            #pragma unroll
            for (int j = 0; j < 4; j++)
                acc[i][j] = __builtin_amdgcn_mfma_f32_16x16x32_bf16(af[i], bf[j], acc[i][j], 0, 0, 0);
        __syncthreads();
    }

    const int rb = bm * 128 + wm + ((lane >> 4) << 2);
    const int cb = bn * 128 + wn + (lane & 15);
    #pragma unroll
    for (int j = 0; j < 4; j++) {
        int col = cb + j * 16;
        if (col < NUM_CLASSES) {
            float bias = base_b[col];
            #pragma unroll
            for (int i = 0; i < 4; i++) {
                int r0 = rb + i * 16;
                out[(size_t)(r0 + 0) * NUM_CLASSES + col] = acc[i][j][0] + bias;
                out[(size_t)(r0 + 1) * NUM_CLASSES + col] = acc[i][j][1] + bias;
                out[(size_t)(r0 + 2) * NUM_CLASSES + col] = acc[i][j][2] + bias;
                out[(size_t)(r0 + 3) * NUM_CLASSES + col] = acc[i][j][3] + bias;
            }
        }
    }
}

extern "C" void kernel_launch(void* const* d_in, const int* in_sizes, int n_in,
                              void* d_out, int out_size, void* d_ws, size_t ws_size,
                              hipStream_t stream) {
    const float* x       = (const float*)d_in[0];
    const float* context = (const float*)d_in[1];
    const float* base_w  = (const float*)d_in[2];
    const float* base_b  = (const float*)d_in[3];
    const float* ctx_w   = (const float*)d_in[4];
    const float* ctx_b   = (const float*)d_in[5];
    const float* ln_g    = (const float*)d_in[6];
    const float* ln_b    = (const float*)d_in[7];
    const float* coeff_w = (const float*)d_in[8];
    const float* coeff_b = (const float*)d_in[9];
    const float* basis_A = (const float*)d_in[10];
    const float* basis_B = (const float*)d_in[11];
    float* out = (float*)d_out;

    uint8_t* ws = (uint8_t*)d_ws;
    const size_t szA    = (size_t)B_ROWS * KE * 2;      // 8,519,680
    const size_t szBext = (size_t)N_PAD * KE * 2;       // 209,264,640
    const size_t szBbt  = (size_t)N_PAD * 32 * 2;       // 3,219,456
    const size_t szCoef = (size_t)B_ROWS * N_BASIS * 4;
    const bool full = ws_size >= szA + szBext + szCoef;

    uint16_t* Aext = (uint16_t*)ws;
    uint16_t* Bbuf = (uint16_t*)(ws + szA);
    float* coeffs  = (float*)(ws + szA + (full ? szBext : szBbt));

    k_cvt_x<<<2048, 256, 0, stream>>>(x, Aext);
    if (full) {
        k_cvt_bw<<<N_PAD, 256, 0, stream>>>(base_w, Bbuf);
        k_cvt_bbt<<<(N_PAD + 255) / 256, 256, 0, stream>>>(basis_B, Bbuf, KE, D_MODEL);
    } else {
        k_cvt_bbt<<<(N_PAD + 255) / 256, 256, 0, stream>>>(basis_B, Bbuf, 32, 0);
    }
    k_ctx<<<2048, HIDDEN, 0, stream>>>(context, ctx_w, ctx_b, ln_g, ln_b,
                                       coeff_w, coeff_b, coeffs);
    k_zu<<<2048, 128, 0, stream>>>(x, basis_A, coeffs, Aext);

    dim3 grid(B_ROWS / 128, N_PAD / 128);   // x = M tiles fastest -> B-tile L2/LLC locality
    if (full) k_gemm<true ><<<grid, 256, 0, stream>>>(Aext, Bbuf, base_w, base_b, out);
    else      k_gemm<false><<<grid, 256, 0, stream>>>(Aext, Bbuf, base_w, base_b, out);
}